// Round 1
// 342.870 us; speedup vs baseline: 1.0385x; 1.0385x over previous
//
#include <hip/hip_runtime.h>
#include <cmath>
#include <algorithm>

#define NUM_LEVELS 16
#define TABLE_SIZE 524288
#define TMASK (TABLE_SIZE - 1)
#define HASH_PRIME 2654435761u
#define T_SAMPLES 192
#define BLOCK 256
#define PTS 64          // points per block; 4 waves split the 16 levels
#define CHUNK 4096      // entries per conversion chunk

typedef _Float16 f16;
typedef f16 f16x2 __attribute__((ext_vector_type(2)));
typedef f16 f16x4 __attribute__((ext_vector_type(4)));
typedef f16 f16x8 __attribute__((ext_vector_type(8)));
typedef float f32x4 __attribute__((ext_vector_type(4)));

struct LvlParams {
    float s[NUM_LEVELS];
    int   res[NUM_LEVELS];
    int   hashed[NUM_LEVELS];
    int   off[NUM_LEVELS];    // entry offset into compact f16 table (4096-aligned)
    int   used[NUM_LEVELS];   // entries actually referenced at this level
};

__device__ __forceinline__ float softplus10(float x) {
    float t = 10.0f * x;
    float e = __expf(-fabsf(t));
    return (fmaxf(t, 0.0f) + __logf(1.0f + e)) * 0.1f;
}

__device__ __forceinline__ void corner_idx(int cx, int cy, int res, int hashed,
                                           int& i00, int& i01, int& i10, int& i11) {
    if (hashed) {
        unsigned hy0 = (unsigned)cy * HASH_PRIME;
        unsigned hy1 = hy0 + HASH_PRIME;           // (cy+1)*PRIME, mul -> add
        i00 = (int)(((unsigned)cx ^ hy0) & TMASK);
        i01 = (int)(((unsigned)cx ^ hy1) & TMASK);
        i10 = (int)(((unsigned)(cx + 1) ^ hy0) & TMASK);
        i11 = (int)(((unsigned)(cx + 1) ^ hy1) & TMASK);
    } else {
        // NOTE: reference has NO bounds clamp; at u=1 on integer-scale levels
        // idx runs past res*res-1 into the table tail. used[] must cover it.
        i00 = cy * res + cx; i10 = i00 + 1;
        i01 = i00 + res;     i11 = i01 + 1;
    }
}

// Packed-f16 bilinear lerp: corners arrive as packed f16 pairs straight from
// the gather (no unpack/dequant); 8 v_pk_fma_f16 instead of ~38 VALU ops.
__device__ __forceinline__ f16x4 lerp4h(f16x4 c00, f16x4 c01, f16x4 c10, f16x4 c11,
                                        float fx, float fy) {
    float gx = 1.0f - fx, gy = 1.0f - fy;
    f16 w00 = (f16)(gx * gy), w01 = (f16)(gx * fy);
    f16 w10 = (f16)(fx * gy), w11 = (f16)(fx * fy);
    f16x4 v00 = {w00, w00, w00, w00}, v01 = {w01, w01, w01, w01};
    f16x4 v10 = {w10, w10, w10, w10}, v11 = {w11, w11, w11, w11};
    return c00 * v00 + c01 * v01 + c10 * v10 + c11 * v11;
}

// fp32 fallback lerp (QT=false path), result rounded to f16 for the MFMA.
__device__ __forceinline__ f16x4 lerp4f(f32x4 c00, f32x4 c01, f32x4 c10, f32x4 c11,
                                        float fx, float fy) {
    float w00 = (1.0f - fx) * (1.0f - fy), w01 = (1.0f - fx) * fy;
    float w10 = fx * (1.0f - fy),          w11 = fx * fy;
    f32x4 a = c00 * w00 + c01 * w01 + c10 * w10 + c11 * w11;
    return __builtin_convertvector(a, f16x4);
}

// ---- prep: pack W0 into MFMA-B-fragment f16 order + spread level params ----
__global__ void prep(const float* __restrict__ W0, f16* __restrict__ w0f,
                     float* __restrict__ sArr, int* __restrict__ resArr,
                     int* __restrict__ hashArr, int* __restrict__ offArr,
                     int* __restrict__ usedArr, LvlParams lp) {
    const int t = threadIdx.x;
    if (t < NUM_LEVELS) {
        sArr[t] = lp.s[t]; resArr[t] = lp.res[t]; hashArr[t] = lp.hashed[t];
        offArr[t] = lp.off[t]; usedArr[t] = lp.used[t];
    }
    #pragma unroll
    for (int i = 0; i < 16; ++i) {
        int f = t * 16 + i;
        int j = f & 7, lx = (f >> 3) & 15, q = (f >> 7) & 3, nt = (f >> 9) & 3, kc = f >> 11;
        int k = kc * 32 + q * 8 + j;
        int n = nt * 16 + lx;
        w0f[f] = (f16)W0[k * 64 + n];
    }
}

// ---- prep_tables: pure streaming f32 -> f16 convert of used entries ----
// (No absmax pass, no shared-mem reduction, no scale array.)
__global__ void prep_tables(const float* __restrict__ emb, f16* __restrict__ embq,
                            const int* __restrict__ offArr, const int* __restrict__ usedArr) {
    const int l    = blockIdx.y;
    const int used = usedArr[l];
    const int base = blockIdx.x * CHUNK;          // entry base within level
    if (base >= used) return;
    const int t = threadIdx.x;
    const float* src = emb + ((size_t)l * TABLE_SIZE + base) * 4;
    f16* dst = embq + (size_t)(offArr[l] + base) * 4;
    #pragma unroll
    for (int i = 0; i < 16; ++i) {
        int e = t + 256 * i;
        if (base + e < used) {
            f32x4 v = *(const f32x4*)(src + (size_t)e * 4);
            *(f16x4*)(dst + (size_t)e * 4) = __builtin_convertvector(v, f16x4);
        }
    }
}

// QT=true: gathers from compact f16 tables (same 8B/entry as the old i16 path,
// but zero dequant VALU: gathered dwords are already packed f16 lerp operands).
template<bool QT>
__launch_bounds__(BLOCK, 8)
__global__ void nerf_fused(const float* __restrict__ x,
                           const float* __restrict__ emb,
                           const f16* __restrict__ embq,
                           const f16* __restrict__ w0f,
                           const float* __restrict__ sArr,
                           const int* __restrict__ resArr,
                           const int* __restrict__ hashArr,
                           const int* __restrict__ offArr,
                           const float* __restrict__ b0,
                           const float* __restrict__ W1,
                           const float* __restrict__ b1,
                           float* __restrict__ out) {
    // Transposed feats tile: feT[level][point][dim], 16*64*4 f16 = 8 KB.
    __shared__ __align__(16) f16 feT[NUM_LEVELS * PTS * 4];

    const int tid  = threadIdx.x;
    const int lane = tid & 63, w = tid >> 6;   // lane = point-in-block

    // ---- ray setup for point = lane (duplicated across 4 waves, L1-hot) ----
    const int gp  = blockIdx.x * PTS + lane;
    const int ray = gp / T_SAMPLES;
    const int t   = gp - ray * T_SAMPLES;

    const float2 o  = *(const float2*)(x + (size_t)ray * (T_SAMPLES * 2));
    const float2 ep = *(const float2*)(x + (size_t)ray * (T_SAMPLES * 2) + (T_SAMPLES - 1) * 2);
    float rdx = ep.x - o.x, rdy = ep.y - o.y;
    float inv = 1.0f / sqrtf(rdx * rdx + rdy * rdy);
    rdx *= inv; rdy *= inv;
    const float z = (float)((double)t * (2.0 / 191.0));
    float px = fminf(fmaxf(o.x + rdx * z, -1.0f), 1.0f);
    float py = fminf(fmaxf(o.y + rdy * z, -1.0f), 1.0f);
    const float ux = (px + 1.0f) * 0.5f;
    const float uy = (py + 1.0f) * 0.5f;

    // this wave's levels: w, w+4, w+8, w+12  (exactly one expensive level each)
    const int l3 = w + 12;

    // ---- level l3 (12..15): issue 4 gathers FIRST, consume LAST ----
    f16x4 c3v[4]; float fx3, fy3;
    {
        float s = sArr[l3];
        float posx = ux * s + 0.5f, posy = uy * s + 0.5f;
        float pfx = floorf(posx), pfy = floorf(posy);
        fx3 = posx - pfx; fy3 = posy - pfy;
        int cx = (int)pfx, cy = (int)pfy;
        int i00, i01, i10, i11;
        corner_idx(cx, cy, resArr[l3], hashArr[l3], i00, i01, i10, i11);
        if (QT) {
            const f16x4* tb = (const f16x4*)embq + offArr[l3];
            c3v[0] = tb[i00]; c3v[1] = tb[i01]; c3v[2] = tb[i10]; c3v[3] = tb[i11];
        } else {
            const f32x4* tb = (const f32x4*)(emb + (size_t)l3 * (TABLE_SIZE * 4));
            f32x4 a = tb[i00], b = tb[i01], c = tb[i10], d = tb[i11];
            c3v[0] = __builtin_convertvector(a, f16x4);
            c3v[1] = __builtin_convertvector(b, f16x4);
            c3v[2] = __builtin_convertvector(c, f16x4);
            c3v[3] = __builtin_convertvector(d, f16x4);
        }
    }

    // ---- levels l2, l1, l0: issue, lerp, write straight to LDS ----
    #pragma unroll
    for (int li = 0; li < 3; ++li) {
        const int l = w + li * 4;              // uniform per wave, all non-hashed
        float s = sArr[l];
        float posx = ux * s + 0.5f, posy = uy * s + 0.5f;
        float pfx = floorf(posx), pfy = floorf(posy);
        float fx = posx - pfx, fy = posy - pfy;
        int cx = (int)pfx, cy = (int)pfy;
        int res = resArr[l];
        int i00 = cy * res + cx, i10 = i00 + 1, i01 = i00 + res, i11 = i01 + 1;
        if (QT) {
            const f16x4* tb = (const f16x4*)embq + offArr[l];
            f16x4 a = tb[i00], b = tb[i01], c = tb[i10], d = tb[i11];
            *(f16x4*)&feT[(l * PTS + lane) * 4] = lerp4h(a, b, c, d, fx, fy);
        } else {
            const f32x4* tb = (const f32x4*)(emb + (size_t)l * (TABLE_SIZE * 4));
            f32x4 a = tb[i00], b = tb[i01], c = tb[i10], d = tb[i11];
            *(f16x4*)&feT[(l * PTS + lane) * 4] = lerp4f(a, b, c, d, fx, fy);
        }
    }

    // ---- consume l3 (its 4 misses have been in flight the whole time) ----
    *(f16x4*)&feT[(l3 * PTS + lane) * 4] = lerp4h(c3v[0], c3v[1], c3v[2], c3v[3], fx3, fy3);

    __syncthreads();   // all 4 waves' feature quarters visible

    // ---- MLP: wave w computes h for its own 16 points (M=16, N=64) ----
    const int lx = lane & 15, q = lane >> 4;
    const int p  = w * 16 + lx;

    f32x4 acc[4];
    #pragma unroll
    for (int nt = 0; nt < 4; ++nt) acc[nt] = (f32x4)(0.0f);

    #pragma unroll
    for (int kc = 0; kc < 2; ++kc) {
        // A-fragment: k = kc*32 + q*8 + j ; feats k = level*4 + dim
        const int la = kc * 8 + 2 * q;
        f16x4 lo = *(const f16x4*)&feT[(la * PTS + p) * 4];
        f16x4 hi = *(const f16x4*)&feT[((la + 1) * PTS + p) * 4];
        f16x8 afr = __builtin_shufflevector(lo, hi, 0, 1, 2, 3, 4, 5, 6, 7);
        #pragma unroll
        for (int nt = 0; nt < 4; ++nt) {
            f16x8 bfr = *(const f16x8*)(w0f + (size_t)(((kc * 4 + nt) * 4 + q) * 16 + lx) * 8);
            acc[nt] = __builtin_amdgcn_mfma_f32_16x16x32_f16(afr, bfr, acc[nt], 0, 0, 0);
        }
    }

    // ---- epilogue: softplus10 -> dot W1 -> reduce over 16 col-lanes ----
    // Constants folded: t = 10*acc + (10*b0);  contribution = (max+log1p) * (0.1*W1)
    float b010[4], w1s[4];
    #pragma unroll
    for (int nt = 0; nt < 4; ++nt) {
        b010[nt] = b0[nt * 16 + lx] * 10.0f;
        w1s[nt]  = W1[nt * 16 + lx] * 0.1f;
    }
    const float b1v = b1[0];
    const float d0 = (float)(1.0 / 192.0);
    const float d1 = (float)(2.0 / 191.0);

    float part[4];
    #pragma unroll
    for (int r = 0; r < 4; ++r) {
        float pp = 0.0f;
        #pragma unroll
        for (int nt = 0; nt < 4; ++nt) {
            float t10 = fmaf(acc[nt][r], 10.0f, b010[nt]);
            float e   = __expf(-fabsf(t10));
            float sp  = fmaxf(t10, 0.0f) + __logf(1.0f + e);
            pp = fmaf(sp, w1s[nt], pp);
        }
        pp += __shfl_xor(pp, 1, 64);
        pp += __shfl_xor(pp, 2, 64);
        pp += __shfl_xor(pp, 4, 64);
        pp += __shfl_xor(pp, 8, 64);
        part[r] = pp;
    }
    if (lx == 0) {
        const int g0 = blockIdx.x * PTS + w * 16 + q * 4;   // multiple of 4
        const int tt = g0 % T_SAMPLES;
        f32x4 ov;
        ov.x = softplus10(part[0] + b1v) * (tt == 0 ? d0 : d1);
        ov.y = softplus10(part[1] + b1v) * d1;
        ov.z = softplus10(part[2] + b1v) * d1;
        ov.w = softplus10(part[3] + b1v) * d1;
        *(f32x4*)(out + g0) = ov;
    }
}

extern "C" void kernel_launch(void* const* d_in, const int* in_sizes, int n_in,
                              void* d_out, int out_size, void* d_ws, size_t ws_size,
                              hipStream_t stream) {
    const float* x   = (const float*)d_in[0];
    const float* emb = (const float*)d_in[1];
    const float* W0  = (const float*)d_in[2];
    const float* b0  = (const float*)d_in[3];
    const float* W1  = (const float*)d_in[4];
    const float* b1  = (const float*)d_in[5];
    float* out = (float*)d_out;

    // ws layout: [0,8192) w0f; [8192,8512) param arrays; embq (f16) at 16384.
    char* ws = (char*)d_ws;
    f16*    w0f    = (f16*)ws;
    float*  sArr   = (float*)(ws + 8192);
    int*    resArr = (int*)(ws + 8256);
    int*    hashArr= (int*)(ws + 8320);
    int*    offArr = (int*)(ws + 8384);
    int*    usedArr= (int*)(ws + 8448);
    f16*    embq   = (f16*)(ws + 16384);

    // Replicate numpy's level constants with the same host libm double ops.
    LvlParams lp;
    const double bb = std::exp((std::log(2048.0) - std::log(2.0)) / 15.0);
    int off = 0, maxUsed = 0;
    for (int l = 0; l < NUM_LEVELS; ++l) {
        double sc = 2.0 * std::pow(bb, (double)l) - 1.0;
        int rr = (int)std::ceil(sc) + 1;
        lp.s[l] = (float)sc;
        lp.res[l] = rr;
        lp.hashed[l] = ((long long)rr * (long long)rr > (long long)TABLE_SIZE) ? 1 : 0;
        int used;
        if (lp.hashed[l]) {
            used = TABLE_SIZE;
        } else {
            // Reference does NOT clamp corners: max idx = cmax*res + cmax where
            // cmax = floor(s+0.5)+1 (reachable at u=1). Cover it, + margin for
            // float(s) vs double(s) coordinate rounding.
            long long cmax = (long long)std::floor(sc + 0.5) + 1;
            long long u = cmax * (long long)rr + cmax + 1 + (rr + 2);
            used = (int)std::min((long long)TABLE_SIZE, u);
        }
        lp.off[l]  = off;
        lp.used[l] = used;
        off += (used + CHUNK - 1) & ~(CHUNK - 1);   // keep chunks level-aligned
        if (used > maxUsed) maxUsed = used;
    }
    const size_t need = 16384 + (size_t)off * 4 * sizeof(f16);   // ~16.5 MB
    const bool useQ = ws_size >= need;

    prep<<<1, 256, 0, stream>>>(W0, w0f, sArr, resArr, hashArr, offArr, usedArr, lp);

    const int nblk = out_size / PTS;   // 1572864/64 = 24576
    if (useQ) {
        dim3 pg((maxUsed + CHUNK - 1) / CHUNK, NUM_LEVELS);
        prep_tables<<<pg, 256, 0, stream>>>(emb, embq, offArr, usedArr);
        nerf_fused<true><<<nblk, BLOCK, 0, stream>>>(x, emb, embq, w0f,
                                                     sArr, resArr, hashArr, offArr,
                                                     b0, W1, b1, out);
    } else {
        nerf_fused<false><<<nblk, BLOCK, 0, stream>>>(x, emb, embq, w0f,
                                                      sArr, resArr, hashArr, offArr,
                                                      b0, W1, b1, out);
    }
}